// Round 7
// baseline (54.822 us; speedup 1.0000x reference)
//
#include <hip/hip_runtime.h>

#define N_ROWS   1024
#define D_DIM    128
#define C_CLS    50000
#define C_PAD    50048
#define NCT64    782        // 50048/64 column tiles (64 cols each)
#define NG       128        // ct groups; 782 = 6*128 + 14
#define NPART    256        // partials per row = NG * 2 col-halves
#define S_SCALE  30.0f
#define M_MARGIN 0.35f
#define EXP2_SCALE 43.2808512266689f   // 30 * log2(e)

typedef short s8v __attribute__((ext_vector_type(8)));   // 8 x bf16 bits (4 VGPRs)
typedef float f4v __attribute__((ext_vector_type(4)));

__device__ inline unsigned short f2bf(float f) {
    unsigned u = __float_as_uint(f);
    u += 0x7FFF + ((u >> 16) & 1);      // round-to-nearest-even (inputs are finite)
    return (unsigned short)(u >> 16);
}
__device__ inline float bf2f(unsigned short h) {
    return __uint_as_float(((unsigned)h) << 16);
}

// ---------------------------------------------------------------------------
// Fused row-normalize: rows [0,C_PAD) = weight -> what (rows >= C_CLS zeroed),
// rows [C_PAD, C_PAD+N_ROWS) = feature -> fhat. One wave per row.
// ---------------------------------------------------------------------------
__global__ void norm_rows_fused(const float* __restrict__ weight,
                                const float* __restrict__ feature,
                                unsigned short* __restrict__ what,
                                unsigned short* __restrict__ fhat) {
    int wid = threadIdx.x >> 6, lane = threadIdx.x & 63;
    int r = blockIdx.x * 4 + wid;
    const float* src;
    unsigned short* dst;
    int srcRow, valid;
    if (r < C_PAD) {                      // wave-uniform branch
        src = weight; dst = what; srcRow = r; valid = (r < C_CLS);
    } else {
        src = feature; dst = fhat; srcRow = r - C_PAD; valid = 1;
    }
    float2 v = make_float2(0.f, 0.f);
    if (valid) v = ((const float2*)src)[(size_t)srcRow * 64 + lane];
    float ss = v.x * v.x + v.y * v.y;
    #pragma unroll
    for (int s = 1; s < 64; s <<= 1) ss += __shfl_xor(ss, s, 64);
    float inv = valid ? 1.0f / fmaxf(sqrtf(ss), 1e-8f) : 0.f;
    ((ushort2*)dst)[(size_t)srcRow * 64 + lane] =
        make_ushort2(f2bf(v.x * inv), f2bf(v.y * inv));
}

// ---------------------------------------------------------------------------
// Barrier-free, LDS-free GEMM+exp. Block (g, rt) = 128 rows x 64 cols per
// tile, tiles ct = g + 128*t. Waves in 2x2: each wave owns 64 rows x 32 cols.
// A fragments loaded global->reg ONCE (L2-resident, 64-B segments). B
// fragments loaded global->reg per tile (8 dwordx4/lane, L1-served for the
// second reader wave), static double-buffer b0/b1 with manually unrolled
// even/odd iterations -> compiler emits counted vmcnt so the t+1 prefetch
// overlaps tile t's MFMA+exp. No __shared__, no __syncthreads anywhere.
// Epilogue: 16-lane shuffle col-reduce, direct write part2[row][2g+wcol].
// Grid linear id = g + 128*rt -> all 8 rt sharing B columns on one XCD.
// ---------------------------------------------------------------------------
__device__ __forceinline__ void loadB(s8v (&B)[8], const char* bRow, int ct) {
    const char* p = bRow + (size_t)ct * 16384;
    B[0] = *(const s8v*)(p);
    B[1] = *(const s8v*)(p + 64);
    B[2] = *(const s8v*)(p + 128);
    B[3] = *(const s8v*)(p + 192);
    B[4] = *(const s8v*)(p + 4096);
    B[5] = *(const s8v*)(p + 4096 + 64);
    B[6] = *(const s8v*)(p + 4096 + 128);
    B[7] = *(const s8v*)(p + 4096 + 192);
}

__device__ __forceinline__ void computeTile(const s8v (&afr)[4][4], const s8v (&B)[8],
                                            float (&esum)[4][4], int ct, int colBase) {
    f4v acc[4][2];
    f4v zero = {0.f, 0.f, 0.f, 0.f};
    #pragma unroll
    for (int m = 0; m < 4; m++) { acc[m][0] = zero; acc[m][1] = zero; }

    #pragma unroll
    for (int kk = 0; kk < 4; kk++)
        #pragma unroll
        for (int m = 0; m < 4; m++) {
            acc[m][0] = __builtin_amdgcn_mfma_f32_16x16x32_bf16(afr[kk][m], B[kk],     acc[m][0], 0, 0, 0);
            acc[m][1] = __builtin_amdgcn_mfma_f32_16x16x32_bf16(afr[kk][m], B[4 + kk], acc[m][1], 0, 0, 0);
        }

    if (ct != NCT64 - 1) {                // fast path: all 32 cols valid
        #pragma unroll
        for (int m = 0; m < 4; m++)
            #pragma unroll
            for (int n = 0; n < 2; n++)
                #pragma unroll
                for (int j = 0; j < 4; j++)
                    esum[m][j] += __builtin_amdgcn_exp2f(EXP2_SCALE * acc[m][n][j]);
    } else {                              // tail tile: mask padded cols
        #pragma unroll
        for (int n = 0; n < 2; n++) {
            int gc = colBase + n * 16;
            #pragma unroll
            for (int m = 0; m < 4; m++)
                #pragma unroll
                for (int j = 0; j < 4; j++)
                    if (gc < C_CLS)
                        esum[m][j] += __builtin_amdgcn_exp2f(EXP2_SCALE * acc[m][n][j]);
        }
    }
}

__global__ __launch_bounds__(256, 2)
void gemm_exp_kernel(const short* __restrict__ fhat,
                     const short* __restrict__ what,
                     float* __restrict__ part2) {
    const int g   = blockIdx.x;           // ct group, 0..127
    const int rt  = blockIdx.y;           // row tile, 0..7
    const int tid = threadIdx.x;
    const int wid = tid >> 6;
    const int lane = tid & 63;
    const int lrow = lane & 15;
    const int kgrp = lane >> 4;
    const int wrow = wid >> 1;            // row half (64 rows)
    const int wcol = wid & 1;             // col half (32 cols)
    const int nt = (g < 14) ? 7 : 6;      // tiles in this group (782 = 6*128+14)

    // ---- A fragments global->reg (once). Rows rt*128 + wrow*64 + m*16 + lrow.
    const char* aBase = (const char*)fhat
        + ((size_t)(rt * 128 + wrow * 64 + lrow)) * 256 + kgrp * 16;
    s8v afr[4][4];
    #pragma unroll
    for (int kk = 0; kk < 4; kk++)
        #pragma unroll
        for (int m = 0; m < 4; m++)
            afr[kk][m] = *(const s8v*)(aBase + m * 4096 + kk * 64);

    // ---- B per-lane row base: B^T row = wcol*32 + n*16 + lrow, chunk kgrp.
    const char* bRow = (const char*)what + ((size_t)(wcol * 32 + lrow)) * 256 + kgrp * 16;

    float esum[4][4];
    #pragma unroll
    for (int m = 0; m < 4; m++)
        #pragma unroll
        for (int j = 0; j < 4; j++) esum[m][j] = 0.f;

    s8v b0[8], b1[8];
    int ct = g;
    const int colBase0 = wcol * 32 + lrow;
    loadB(b0, bRow, ct);
    int t = 0;
    while (true) {
        if (t + 1 < nt) loadB(b1, bRow, ct + 128);
        computeTile(afr, b0, esum, ct, ct * 64 + colBase0);
        if (++t >= nt) break;
        ct += 128;
        if (t + 1 < nt) loadB(b0, bRow, ct + 128);
        computeTile(afr, b1, esum, ct, ct * 64 + colBase0);
        if (++t >= nt) break;
        ct += 128;
    }

    // ---- epilogue: reduce esum over the wave's 16 col-lanes, direct write.
    #pragma unroll
    for (int m = 0; m < 4; m++)
        #pragma unroll
        for (int j = 0; j < 4; j++) {
            float v = esum[m][j];
            v += __shfl_xor(v, 1, 64);
            v += __shfl_xor(v, 2, 64);
            v += __shfl_xor(v, 4, 64);
            v += __shfl_xor(v, 8, 64);
            if (lrow == 0) {
                int row = rt * 128 + wrow * 64 + m * 16 + kgrp * 4 + j;
                part2[(size_t)row * NPART + g * 2 + wcol] = v;
            }
        }
}

// ---------------------------------------------------------------------------
// One wave per row: S_n = sum of 256 partials (4 per lane); cos_y via fp32
// dot of the SAME bf16 normalized vectors; center loss on fp32 inputs.
// rowval[n] = (lse_n - t_n)/N + 0.005 * ||f_n - w_y||^2
// ---------------------------------------------------------------------------
__global__ void finalize_rows_kernel(const float* __restrict__ part2,
                                     const unsigned short* __restrict__ fhat,
                                     const unsigned short* __restrict__ what,
                                     const float* __restrict__ feature,
                                     const float* __restrict__ weight,
                                     const int* __restrict__ label,
                                     float* __restrict__ rowval) {
    int wid = threadIdx.x >> 6, lane = threadIdx.x & 63;
    int n = blockIdx.x * 4 + wid;
    int y = label[n];

    const float* p = part2 + (size_t)n * NPART;
    float S = p[lane] + p[64 + lane] + p[128 + lane] + p[192 + lane];

    float2 f2 = ((const float2*)feature)[(size_t)n * 64 + lane];
    float2 w2 = ((const float2*)weight)[(size_t)y * 64 + lane];
    float dx = f2.x - w2.x, dy = f2.y - w2.y;
    float cl = dx * dx + dy * dy;

    ushort2 fh = ((const ushort2*)fhat)[(size_t)n * 64 + lane];
    ushort2 wh = ((const ushort2*)what)[(size_t)y * 64 + lane];
    float cy = bf2f(fh.x) * bf2f(wh.x) + bf2f(fh.y) * bf2f(wh.y);

    #pragma unroll
    for (int s = 1; s < 64; s <<= 1) {
        S  += __shfl_xor(S, s, 64);
        cl += __shfl_xor(cl, s, 64);
        cy += __shfl_xor(cy, s, 64);
    }
    if (lane == 0) {
        float t  = S_SCALE * (cy - M_MARGIN);
        float Sp = S - __expf(S_SCALE * cy) + __expf(t);
        rowval[n] = (logf(Sp) - t) * (1.0f / (float)N_ROWS) + 0.005f * cl;
    }
}

__global__ void reduce_final_kernel(const float* __restrict__ rowval, float* __restrict__ out) {
    __shared__ float sbuf[4];
    int t = threadIdx.x;
    float v = rowval[t] + rowval[t + 256] + rowval[t + 512] + rowval[t + 768];
    #pragma unroll
    for (int s = 1; s < 64; s <<= 1) v += __shfl_xor(v, s, 64);
    if ((t & 63) == 0) sbuf[t >> 6] = v;
    __syncthreads();
    if (t == 0) out[0] = sbuf[0] + sbuf[1] + sbuf[2] + sbuf[3];
}

// ---------------------------------------------------------------------------
extern "C" void kernel_launch(void* const* d_in, const int* in_sizes, int n_in,
                              void* d_out, int out_size, void* d_ws, size_t ws_size,
                              hipStream_t stream) {
    const float* feature = (const float*)d_in[0];
    const float* weight  = (const float*)d_in[1];
    const int*   label   = (const int*)d_in[2];

    // Workspace layout (bytes):
    //   what   [0,        12812288)  : 50048*128*2
    //   fhat   [12812288, 13074432)  : 1024*128*2
    //   part2  [13074432, 14123008)  : 1024*256*4
    //   rowval [14123008, 14127104)  : 1024*4
    const size_t WS_NEEDED = 14127104;
    if (ws_size < WS_NEEDED) return;   // defensive: visible failure, not OOB writes

    char* ws = (char*)d_ws;
    unsigned short* what = (unsigned short*)ws;
    unsigned short* fhat = (unsigned short*)(ws + 12812288);
    float*         part2 = (float*)(ws + 13074432);
    float*        rowval = (float*)(ws + 14123008);

    norm_rows_fused<<<dim3((C_PAD + N_ROWS) / 4), 256, 0, stream>>>(weight, feature, what, fhat);
    gemm_exp_kernel<<<dim3(NG, 8), 256, 0, stream>>>((const short*)fhat, (const short*)what, part2);
    finalize_rows_kernel<<<dim3(N_ROWS / 4), 256, 0, stream>>>(part2, fhat, what, feature, weight,
                                                               label, rowval);
    reduce_final_kernel<<<1, 256, 0, stream>>>(rowval, (float*)d_out);
}

// Round 8
// 38.530 us; speedup vs baseline: 1.4228x; 1.4228x over previous
//
#include <hip/hip_runtime.h>

#define N_ROWS   1024
#define D_DIM    128
#define C_CLS    50000
#define C_PAD    50048
#define NCT64    782        // 50048/64 column tiles (64 cols each)
#define NG       96         // ct groups; 782 = 8*96 + 14
#define NPART    192        // partials per row = NG * 2 col-halves
#define S_SCALE  30.0f
#define M_MARGIN 0.35f
#define EXP2_SCALE 43.2808512266689f   // 30 * log2(e)

typedef short s8v __attribute__((ext_vector_type(8)));   // 8 x bf16 bits (4 VGPRs)
typedef float f4v __attribute__((ext_vector_type(4)));

__device__ inline unsigned short f2bf(float f) {
    unsigned u = __float_as_uint(f);
    u += 0x7FFF + ((u >> 16) & 1);      // round-to-nearest-even (inputs are finite)
    return (unsigned short)(u >> 16);
}
__device__ inline float bf2f(unsigned short h) {
    return __uint_as_float(((unsigned)h) << 16);
}
__device__ inline void load_lds16(const char* src, unsigned char* lds) {
    __builtin_amdgcn_global_load_lds(
        (const __attribute__((address_space(1))) void*)src,
        (__attribute__((address_space(3))) void*)lds, 16, 0, 0);
}

// ---------------------------------------------------------------------------
// Fused row-normalize: rows [0,C_PAD) = weight -> what (rows >= C_CLS zeroed),
// rows [C_PAD, C_PAD+N_ROWS) = feature -> fhat. One wave per row.
// ---------------------------------------------------------------------------
__global__ void norm_rows_fused(const float* __restrict__ weight,
                                const float* __restrict__ feature,
                                unsigned short* __restrict__ what,
                                unsigned short* __restrict__ fhat) {
    int wid = threadIdx.x >> 6, lane = threadIdx.x & 63;
    int r = blockIdx.x * 4 + wid;
    const float* src;
    unsigned short* dst;
    int srcRow, valid;
    if (r < C_PAD) {                      // wave-uniform branch
        src = weight; dst = what; srcRow = r; valid = (r < C_CLS);
    } else {
        src = feature; dst = fhat; srcRow = r - C_PAD; valid = 1;
    }
    float2 v = make_float2(0.f, 0.f);
    if (valid) v = ((const float2*)src)[(size_t)srcRow * 64 + lane];
    float ss = v.x * v.x + v.y * v.y;
    #pragma unroll
    for (int s = 1; s < 64; s <<= 1) ss += __shfl_xor(ss, s, 64);
    float inv = valid ? 1.0f / fmaxf(sqrtf(ss), 1e-8f) : 0.f;
    ((ushort2*)dst)[(size_t)srcRow * 64 + lane] =
        make_ushort2(f2bf(v.x * inv), f2bf(v.y * inv));
}

// ---------------------------------------------------------------------------
// ct-loop GEMM+exp, T3/T4 pipeline. Block (g, rt): 128 rows x 64 cols per
// tile, tiles ct = g + 96*t (8-9 tiles). A (128x128 = 32KB) staged once
// through LDS into registers. B tiles (64 rows x 128 K = 16KB) cycle through
// THREE 16KB LDS buffers, staged 2-ahead with global_load_lds (XOR swizzle
// on the GLOBAL source per rule #21, linear LDS dest, swizzled ds_read).
// Per tile: counted s_waitcnt vmcnt(4) (NEVER 0 mid-loop) -> one raw
// s_barrier -> issue stage(t+2) -> ds_read+MFMA+exp. WAR safe: a wave at
// barrier t has consumed its t-1 reads, so buf[(t+2)%3]=buf[(t-1)%3] is free.
// Wave layout 2x2: wave owns 64 rows x 32 cols -> reads only 8KB/tile (2x
// less ds_read than 4x1). Epilogue: 16-lane shuffle col-reduce, direct write.
// Grid 96x8 = 768 blocks = exactly 3/CU (LDS 48KB); 96 % 8 == 0 keeps all
// 8 rt sharing a B tile on one XCD.
// ---------------------------------------------------------------------------
__global__ __launch_bounds__(256, 3)
void gemm_exp_kernel(const short* __restrict__ fhat,
                     const short* __restrict__ what,
                     float* __restrict__ part2) {
    __shared__ __align__(16) unsigned char smem[49152];   // 3 x 16KB B buffers
    const int g   = blockIdx.x;           // ct group, 0..95
    const int rt  = blockIdx.y;           // row tile, 0..7
    const int tid = threadIdx.x;
    const int wid = tid >> 6;
    const int lane = tid & 63;
    const int lrow = lane & 15;
    const int kgrp = lane >> 4;
    const int wrow = wid >> 1;            // row half (64 rows)
    const int wcol = wid & 1;             // col half (32 cols)
    const int nt = (g < 14) ? 9 : 8;      // tiles in this group (782 = 8*96+14)

    const char* aSrc  = (const char*)fhat + (size_t)rt * 32768;
    const char* bBase = (const char*)what;

    // ---- prologue: A tile (32KB) -> smem[0..32K), then A -> registers ----
    #pragma unroll
    for (int i = 0; i < 8; i++) {
        int o = wid * 8192 + i * 1024 + lane * 16;
        int s = o ^ (((o >> 8) & 7) << 4);      // source pre-swizzle (involution)
        load_lds16(aSrc + s, smem + o);
    }
    __syncthreads();

    s8v afr[4][4];                        // wave rows: wrow*64 + m*16 + lrow
    #pragma unroll
    for (int kk = 0; kk < 4; kk++)
        #pragma unroll
        for (int m = 0; m < 4; m++) {
            int row = wrow * 64 + m * 16 + lrow;
            int b = (row * 256 + kk * 64 + kgrp * 16) ^ ((row & 7) << 4);
            afr[kk][m] = *(const s8v*)(smem + b);
        }
    __syncthreads();                      // afr reads retired; smem reusable

    // ---- stage B(t=0) -> buf0, B(t=1) -> buf1 (4 loads/wave each) ----
    #pragma unroll
    for (int i = 0; i < 4; i++) {
        int o = wid * 4096 + i * 1024 + lane * 16;
        int s = o ^ (((o >> 8) & 7) << 4);
        load_lds16(bBase + (size_t)g * 16384 + s, smem + o);
        load_lds16(bBase + (size_t)(g + 96) * 16384 + s, smem + 16384 + o);
    }

    float esum[4][4];
    #pragma unroll
    for (int m = 0; m < 4; m++)
        #pragma unroll
        for (int j = 0; j < 4; j++) esum[m][j] = 0.f;

    for (int t = 0; t < nt; ++t) {
        const int ct = g + 96 * t;
        // counted wait: tile t's 4 loads done; t+1's 4 may stay in flight
        if (t + 1 < nt) asm volatile("s_waitcnt vmcnt(4)" ::: "memory");
        else            asm volatile("s_waitcnt vmcnt(0)" ::: "memory");
        __builtin_amdgcn_s_barrier();     // tile t fully in LDS, buf[(t+2)%3] free
        __builtin_amdgcn_sched_barrier(0);

        if (t + 2 < nt) {                 // stage t+2 BEFORE compute (T3 order)
            const char* src = bBase + (size_t)(ct + 192) * 16384;
            unsigned char* dstb = smem + ((t + 2) % 3) * 16384;
            #pragma unroll
            for (int i = 0; i < 4; i++) {
                int o = wid * 4096 + i * 1024 + lane * 16;
                int s = o ^ (((o >> 8) & 7) << 4);
                load_lds16(src + s, dstb + o);
            }
        }

        const unsigned char* bb = smem + (t % 3) * 16384;
        f4v acc[4][2];
        f4v zero = {0.f, 0.f, 0.f, 0.f};
        #pragma unroll
        for (int m = 0; m < 4; m++) { acc[m][0] = zero; acc[m][1] = zero; }

        #pragma unroll
        for (int kk = 0; kk < 4; kk++) {
            s8v bfr[2];
            #pragma unroll
            for (int n = 0; n < 2; n++) {
                int row = wcol * 32 + n * 16 + lrow;   // B^T row = output col
                int b = (row * 256 + kk * 64 + kgrp * 16) ^ ((row & 7) << 4);
                bfr[n] = *(const s8v*)(bb + b);
            }
            #pragma unroll
            for (int m = 0; m < 4; m++) {
                acc[m][0] = __builtin_amdgcn_mfma_f32_16x16x32_bf16(
                    afr[kk][m], bfr[0], acc[m][0], 0, 0, 0);
                acc[m][1] = __builtin_amdgcn_mfma_f32_16x16x32_bf16(
                    afr[kk][m], bfr[1], acc[m][1], 0, 0, 0);
            }
        }

        if (ct != NCT64 - 1) {            // fast path: all 32 cols valid
            #pragma unroll
            for (int m = 0; m < 4; m++)
                #pragma unroll
                for (int n = 0; n < 2; n++)
                    #pragma unroll
                    for (int j = 0; j < 4; j++)
                        esum[m][j] += __builtin_amdgcn_exp2f(EXP2_SCALE * acc[m][n][j]);
        } else {                          // tail tile: mask padded cols
            #pragma unroll
            for (int n = 0; n < 2; n++) {
                int gc = ct * 64 + wcol * 32 + n * 16 + lrow;
                #pragma unroll
                for (int m = 0; m < 4; m++)
                    #pragma unroll
                    for (int j = 0; j < 4; j++)
                        if (gc < C_CLS)
                            esum[m][j] += __builtin_amdgcn_exp2f(EXP2_SCALE * acc[m][n][j]);
            }
        }
    }

    // ---- epilogue: reduce over the wave's 16 col-lanes, direct write ----
    #pragma unroll
    for (int m = 0; m < 4; m++)
        #pragma unroll
        for (int j = 0; j < 4; j++) {
            float v = esum[m][j];
            v += __shfl_xor(v, 1, 64);
            v += __shfl_xor(v, 2, 64);
            v += __shfl_xor(v, 4, 64);
            v += __shfl_xor(v, 8, 64);
            if (lrow == 0) {
                int row = rt * 128 + wrow * 64 + m * 16 + kgrp * 4 + j;
                part2[(size_t)row * NPART + g * 2 + wcol] = v;
            }
        }
}

// ---------------------------------------------------------------------------
// One wave per row: S_n = sum of 192 partials (3 per lane); cos_y via fp32
// dot of the SAME bf16 normalized vectors; center loss on fp32 inputs.
// rowval[n] = (lse_n - t_n)/N + 0.005 * ||f_n - w_y||^2
// ---------------------------------------------------------------------------
__global__ void finalize_rows_kernel(const float* __restrict__ part2,
                                     const unsigned short* __restrict__ fhat,
                                     const unsigned short* __restrict__ what,
                                     const float* __restrict__ feature,
                                     const float* __restrict__ weight,
                                     const int* __restrict__ label,
                                     float* __restrict__ rowval) {
    int wid = threadIdx.x >> 6, lane = threadIdx.x & 63;
    int n = blockIdx.x * 4 + wid;
    int y = label[n];

    const float* p = part2 + (size_t)n * NPART;
    float S = p[lane] + p[64 + lane] + p[128 + lane];

    float2 f2 = ((const float2*)feature)[(size_t)n * 64 + lane];
    float2 w2 = ((const float2*)weight)[(size_t)y * 64 + lane];
    float dx = f2.x - w2.x, dy = f2.y - w2.y;
    float cl = dx * dx + dy * dy;

    ushort2 fh = ((const ushort2*)fhat)[(size_t)n * 64 + lane];
    ushort2 wh = ((const ushort2*)what)[(size_t)y * 64 + lane];
    float cy = bf2f(fh.x) * bf2f(wh.x) + bf2f(fh.y) * bf2f(wh.y);

    #pragma unroll
    for (int s = 1; s < 64; s <<= 1) {
        S  += __shfl_xor(S, s, 64);
        cl += __shfl_xor(cl, s, 64);
        cy += __shfl_xor(cy, s, 64);
    }
    if (lane == 0) {
        float t  = S_SCALE * (cy - M_MARGIN);
        float Sp = S - __expf(S_SCALE * cy) + __expf(t);
        rowval[n] = (logf(Sp) - t) * (1.0f / (float)N_ROWS) + 0.005f * cl;
    }
}

__global__ void reduce_final_kernel(const float* __restrict__ rowval, float* __restrict__ out) {
    __shared__ float sbuf[4];
    int t = threadIdx.x;
    float v = rowval[t] + rowval[t + 256] + rowval[t + 512] + rowval[t + 768];
    #pragma unroll
    for (int s = 1; s < 64; s <<= 1) v += __shfl_xor(v, s, 64);
    if ((t & 63) == 0) sbuf[t >> 6] = v;
    __syncthreads();
    if (t == 0) out[0] = sbuf[0] + sbuf[1] + sbuf[2] + sbuf[3];
}

// ---------------------------------------------------------------------------
extern "C" void kernel_launch(void* const* d_in, const int* in_sizes, int n_in,
                              void* d_out, int out_size, void* d_ws, size_t ws_size,
                              hipStream_t stream) {
    const float* feature = (const float*)d_in[0];
    const float* weight  = (const float*)d_in[1];
    const int*   label   = (const int*)d_in[2];

    // Workspace layout (bytes):
    //   what   [0,        12812288)  : 50048*128*2
    //   fhat   [12812288, 13074432)  : 1024*128*2
    //   part2  [13074432, 13860864)  : 1024*192*4
    //   rowval [13860864, 13864960)  : 1024*4
    const size_t WS_NEEDED = 13864960;
    if (ws_size < WS_NEEDED) return;   // defensive: visible failure, not OOB writes

    char* ws = (char*)d_ws;
    unsigned short* what = (unsigned short*)ws;
    unsigned short* fhat = (unsigned short*)(ws + 12812288);
    float*         part2 = (float*)(ws + 13074432);
    float*        rowval = (float*)(ws + 13860864);

    norm_rows_fused<<<dim3((C_PAD + N_ROWS) / 4), 256, 0, stream>>>(weight, feature, what, fhat);
    gemm_exp_kernel<<<dim3(NG, 8), 256, 0, stream>>>((const short*)fhat, (const short*)what, part2);
    finalize_rows_kernel<<<dim3(N_ROWS / 4), 256, 0, stream>>>(part2, fhat, what, feature, weight,
                                                               label, rowval);
    reduce_final_kernel<<<1, 256, 0, stream>>>(rowval, (float*)d_out);
}